// Round 12
// baseline (262.106 us; speedup 1.0000x reference)
//
#include <hip/hip_runtime.h>
#include <stdint.h>

typedef unsigned short u16;
typedef unsigned int   u32;

typedef __bf16 bf16x8 __attribute__((ext_vector_type(8)));
typedef float  fx4    __attribute__((ext_vector_type(4)));
typedef u16    u16x8  __attribute__((ext_vector_type(8)));
typedef u16    u16x4  __attribute__((ext_vector_type(4)));

__device__ __forceinline__ float b2f(u32 bits) {
  union { u32 i; float f; } v; v.i = bits << 16; return v.f;
}
__device__ __forceinline__ u16 f2b(float f) {
  union { float f; u32 i; } v; v.f = f;
  u32 x = v.i;
  return (u16)((x + 0x7fffu + ((x >> 16) & 1u)) >> 16);  // RNE (sw)
}
__device__ __forceinline__ u16 f2b_hw(float f) {
  union { __bf16 b; u16 u; } v; v.b = (__bf16)f; return v.u;
}

// ---------------------------------------------------------------------------
// Packed fragment layout (flatmm-style, AITER s02 pattern): for matrix X[R][K]
// (K=2048, KT=64 k-tiles of 32), fragment-packed element address:
//   P(r64, kt, t, lane, j) = (((r64*64 + kt)*4 + t)*64 + lane)*8 + j
// holding X[r64*64 + t*16 + (lane&15)][kt*32 + (lane>>4)*8 + j].
// A wave reads its 4 fragments for (r64, kt) as 4 coalesced 1KB loads.
// ---------------------------------------------------------------------------

// ---------------------------------------------------------------------------
// Cast f32 -> bf16 AND pack into fragment order: x -> xp, Wq/Wk/Wv -> wqkvp
// (rows n' = n | 2048+n | 2560+n), Wo -> wop. Sizes: x 4.2M, QKV 6.3M, Wo 4.2M.
// ---------------------------------------------------------------------------
__global__ __launch_bounds__(256) void cast_pack_kernel(
    const float* __restrict__ s0, const float* __restrict__ s1,
    const float* __restrict__ s2, const float* __restrict__ s3,
    const float* __restrict__ s4, u16* __restrict__ xp,
    u16* __restrict__ wqkvp, u16* __restrict__ wop)
{
  const size_t i8 = ((size_t)blockIdx.x * 256 + threadIdx.x) * 8;
  if (i8 >= 14680064) return;
  const float* src; size_t off; u16* dst; int nbase;
  if      (i8 <  4194304) { src = s0; off = i8;            dst = xp;    nbase = 0; }
  else if (i8 <  8388608) { src = s1; off = i8 - 4194304;  dst = wqkvp; nbase = 0; }
  else if (i8 <  9437184) { src = s2; off = i8 - 8388608;  dst = wqkvp; nbase = 2048; }
  else if (i8 < 10485760) { src = s3; off = i8 - 9437184;  dst = wqkvp; nbase = 2560; }
  else                    { src = s4; off = i8 - 10485760; dst = wop;   nbase = 0; }

  const float4 a = *(const float4*)(src + off);
  const float4 b = *(const float4*)(src + off + 4);
  u16x8 o;
  o[0] = f2b(a.x); o[1] = f2b(a.y); o[2] = f2b(a.z); o[3] = f2b(a.w);
  o[4] = f2b(b.x); o[5] = f2b(b.y); o[6] = f2b(b.z); o[7] = f2b(b.w);

  const int n  = nbase + (int)(off >> 11);       // packed row
  const int k  = (int)(off & 2047);              // 8-aligned
  const int n64 = n >> 6, t = (n >> 4) & 3;
  const int kt = k >> 5, quad = (k >> 3) & 3;
  const int lane = quad * 16 + (n & 15);
  const size_t dest = ((((size_t)n64 * 64 + kt) * 4 + t) * 64 + lane) * 8;
  *(u16x8*)(dst + dest) = o;
}

// ---------------------------------------------------------------------------
// Flatmm bf16 MFMA GEMM: C[M,N] = A*B^T with BOTH operands fragment-packed.
// No LDS, no barriers, no DMA: per wave per k-tile, 8 coalesced 1KB global
// loads (4 A-frags + 4 B-frags) + 16 MFMAs. 2-iter register ping-pong hides
// L2 latency; waves are fully independent (the barrier-ordered LDS staging
// was the structural stall: 3-buf == 4-buf == neutral, m131-m141 pattern).
// Each block = 4 waves = 2x2 of 64x64 tiles (128x128 per block).
// MODE 0: QKV epilogue -- RoPE fused (Q pre-scaled 2^-3), V transposed to vt.
// MODE 1: plain f32 store (output projection).
// ---------------------------------------------------------------------------
template <int MODE>
__global__ __launch_bounds__(256) void gemm_flat(
    const u16* __restrict__ Ap, const u16* __restrict__ Bp,
    void* __restrict__ Cv, int ldc,
    const float* __restrict__ cosb, const float* __restrict__ sinb,
    u16* __restrict__ vtg)
{
  const int tid  = threadIdx.x;
  const int wave = tid >> 6, lane = tid & 63;
  const int wm = wave >> 1, wn = wave & 1;
  const int quad = lane >> 4, l16 = lane & 15;

  const int m64 = blockIdx.y * 2 + wm;
  const int n64 = blockIdx.x * 2 + wn;

  // per-(r64) fragment base: stride per kt = 4*64*8 = 2048 elems, per t = 512
  const u16* ap = Ap + (size_t)m64 * 131072 + lane * 8;
  const u16* bp = Bp + (size_t)n64 * 131072 + lane * 8;

  fx4 acc[4][4];
#pragma unroll
  for (int i = 0; i < 4; ++i)
#pragma unroll
    for (int j = 0; j < 4; ++j) acc[i][j] = fx4{0.f, 0.f, 0.f, 0.f};

  bf16x8 a0[4], b0[4], a1[4], b1[4];
#pragma unroll
  for (int t = 0; t < 4; ++t) {
    a0[t] = *(const bf16x8*)(ap + t * 512);
    b0[t] = *(const bf16x8*)(bp + t * 512);
  }

#pragma unroll 1
  for (int kt = 0; kt < 64; kt += 2) {
    const u16* ap1 = ap + (size_t)(kt + 1) * 2048;
    const u16* bp1 = bp + (size_t)(kt + 1) * 2048;
#pragma unroll
    for (int t = 0; t < 4; ++t) {           // prefetch kt+1 (always valid)
      a1[t] = *(const bf16x8*)(ap1 + t * 512);
      b1[t] = *(const bf16x8*)(bp1 + t * 512);
    }
#pragma unroll
    for (int ti = 0; ti < 4; ++ti)
#pragma unroll
      for (int tj = 0; tj < 4; ++tj)
        acc[ti][tj] = __builtin_amdgcn_mfma_f32_16x16x32_bf16(
            a0[ti], b0[tj], acc[ti][tj], 0, 0, 0);
    if (kt < 62) {
      const u16* ap2 = ap + (size_t)(kt + 2) * 2048;
      const u16* bp2 = bp + (size_t)(kt + 2) * 2048;
#pragma unroll
      for (int t = 0; t < 4; ++t) {         // prefetch kt+2
        a0[t] = *(const bf16x8*)(ap2 + t * 512);
        b0[t] = *(const bf16x8*)(bp2 + t * 512);
      }
    }
#pragma unroll
    for (int ti = 0; ti < 4; ++ti)
#pragma unroll
      for (int tj = 0; tj < 4; ++tj)
        acc[ti][tj] = __builtin_amdgcn_mfma_f32_16x16x32_bf16(
            a1[ti], b1[tj], acc[ti][tj], 0, 0, 0);
  }

  const int m0 = blockIdx.y * 128;
  const int n0 = blockIdx.x * 128;

  if (MODE == 1) {                     // plain f32 store (out-proj)
    float* C = (float*)Cv;
#pragma unroll
    for (int ti = 0; ti < 4; ++ti) {
      const int row_b = m0 + wm * 64 + ti * 16 + quad * 4;
#pragma unroll
      for (int tj = 0; tj < 4; ++tj) {
        const int col = n0 + wn * 64 + tj * 16 + l16;
#pragma unroll
        for (int r = 0; r < 4; ++r)
          C[(size_t)(row_b + r) * ldc + col] = acc[ti][tj][r];
      }
    }
  } else {                             // QKV epilogue
    u16* C = (u16*)Cv;
    const int cb = n0 + wn * 64;       // wave's 64-col span = one head block
    if (cb < 2560) {                   // Q or K: fuse RoPE (+2^-3 scale for Q)
      const float qs = (cb < 2048) ? 0.125f : 1.0f;
#pragma unroll
      for (int ti = 0; ti < 4; ++ti) {
#pragma unroll
        for (int r = 0; r < 4; ++r) {
          const int s = m0 + wm * 64 + ti * 16 + quad * 4 + r;
          const float* cr = cosb + s * 64;
          const float* sr = sinb + s * 64;
          u16* orow = C + (size_t)s * 3072 + cb;
#pragma unroll
          for (int tj = 0; tj < 2; ++tj) {
            const int d0 = tj * 16 + l16, d1 = d0 + 32;
            const float x0 = acc[ti][tj][r], x1 = acc[ti][tj + 2][r];
            orow[d0] = f2b((x0 * cr[d0] - x1 * sr[d0]) * qs);
            orow[d1] = f2b((x1 * cr[d1] + x0 * sr[d1]) * qs);
          }
        }
      }
    } else {                           // V: store TRANSPOSED to vt[d][key]
      const int vr0 = cb - 2560;
#pragma unroll
      for (int ti = 0; ti < 4; ++ti) {
        const int s0 = m0 + wm * 64 + ti * 16 + quad * 4;
#pragma unroll
        for (int tj = 0; tj < 4; ++tj) {
          const int vr = vr0 + tj * 16 + l16;
          u16x4 o;
#pragma unroll
          for (int r = 0; r < 4; ++r) o[r] = f2b(acc[ti][tj][r]);
          *(u16x4*)(vtg + (size_t)vr * 2048 + s0) = o;
        }
      }
    }
  }
}

// ---------------------------------------------------------------------------
// MFMA causal flash attention (r11 structure, unchanged compute). Block =
// head h + TWO q-tiles (b and 31-b) = exactly 17 staging iters. Sync staging,
// 128-key tiles. Exact shift-by-0 softmax; hw bf16 cvt; diagonal-only mask.
// EPILOGUE CHANGE: O stored to attnbuf in fragment-PACKED A-operand layout
// (out-proj reads it directly global->VGPR). Index map verified:
//   lane=((col>>3)&3)*16+(qg&15), j=col&7, t=(qg>>4)&3, kt=col>>5.
// ---------------------------------------------------------------------------
__global__ __launch_bounds__(256) void attn_kernel(
    const u16* __restrict__ qkv, const u16* __restrict__ vt,
    u16* __restrict__ attnbuf)
{
  const int h   = blockIdx.y;
  const int kvh = h >> 2;                  // GQA group = 4
  const int tid = threadIdx.x;
  const int w = tid >> 6, lane = tid & 63;
  const int quad = lane >> 4, l16 = lane & 15;

  __shared__ __align__(16) u16 Qs[64][72];
  __shared__ __align__(16) u16 Ks[128][72];
  __shared__ __align__(16) u16 Vh[2][64][72];
  __shared__ __align__(16) u16 Ps[4][16][72];

  const int kcol = 2048 + kvh * 64;

#pragma unroll 1
  for (int pass = 0; pass < 2; ++pass) {
    const int bx = pass ? (31 - blockIdx.x) : blockIdx.x;
    const int r0 = bx * 64;
    const int nhalf  = bx + 1;           // 64-key halves to process
    const int ntiles = (bx + 2) >> 1;    // 128-key tiles to stage

    __syncthreads();                     // prev pass's LDS reads done

    // stage Q (already 2^-3-scaled by the QKV epilogue)
#pragma unroll
    for (int i = 0; i < 2; ++i) {
      const int idx = tid + i * 256;
      const int r = idx >> 3, dc = (idx & 7) * 8;
      *(uint4*)&Qs[r][dc] =
          *(const uint4*)(qkv + (size_t)(r0 + r) * 3072 + h * 64 + dc);
    }

    fx4 O[4];
    float l_r[4];
#pragma unroll
    for (int c = 0; c < 4; ++c) O[c] = fx4{0.f, 0.f, 0.f, 0.f};
#pragma unroll
    for (int r = 0; r < 4; ++r) l_r[r] = 0.f;

#pragma unroll 1
    for (int kt = 0; kt < ntiles; ++kt) {
      const int k0 = kt * 128;
      __syncthreads();                   // prev stage's LDS reads done
      // stage K: 128 rows x 64 dims (1024 x 16B chunks)
#pragma unroll
      for (int i = 0; i < 4; ++i) {
        const int idx = tid + i * 256;
        const int j = idx >> 3, dc = (idx & 7) * 8;
        *(uint4*)&Ks[j][dc] =
            *(const uint4*)(qkv + (size_t)(k0 + j) * 3072 + kcol + dc);
      }
      // stage V: 64 dims x 128 keys as two 64x64 half-tiles
#pragma unroll
      for (int i = 0; i < 4; ++i) {
        const int idx = tid + i * 256;
        const int hh = idx >> 9, rem = idx & 511;
        const int j = rem >> 3, dc = (rem & 7) * 8;
        *(uint4*)&Vh[hh][j][dc] =
            *(const uint4*)(vt + (size_t)(kvh * 64 + j) * 2048 + k0 + hh * 64 + dc);
      }
      __syncthreads();                   // publish (single vmcnt drain / 128 keys)

      const bf16x8 aq0 = *(const bf16x8*)&Qs[w * 16 + l16][quad * 8];
      const bf16x8 aq1 = *(const bf16x8*)&Qs[w * 16 + l16][32 + quad * 8];

#pragma unroll
      for (int hh = 0; hh < 2; ++hh) {
        const int half = kt * 2 + hh;
        if (half < nhalf) {
          const int k0h = k0 + hh * 64;

          // QK^T: scores for 16 q-rows x 64 keys
          fx4 sc[4];
#pragma unroll
          for (int c = 0; c < 4; ++c) {
            const bf16x8 b0 = *(const bf16x8*)&Ks[hh * 64 + c * 16 + l16][quad * 8];
            const bf16x8 b1 = *(const bf16x8*)&Ks[hh * 64 + c * 16 + l16][32 + quad * 8];
            fx4 z = fx4{0.f, 0.f, 0.f, 0.f};
            z     = __builtin_amdgcn_mfma_f32_16x16x32_bf16(aq0, b0, z, 0, 0, 0);
            sc[c] = __builtin_amdgcn_mfma_f32_16x16x32_bf16(aq1, b1, z, 0, 0, 0);
          }

          // p = exp(s); causal mask only on the diagonal half (block-uniform).
          if (k0h >= r0) {
#pragma unroll
            for (int c = 0; c < 4; ++c)
#pragma unroll
              for (int r = 0; r < 4; ++r) {
                float p = __expf(sc[c][r]);
                if (k0h + c * 16 + l16 > r0 + w * 16 + quad * 4 + r) p = 0.f;
                l_r[r] += p;
                Ps[w][quad * 4 + r][c * 16 + l16] = f2b_hw(p);
              }
          } else {
#pragma unroll
            for (int c = 0; c < 4; ++c)
#pragma unroll
              for (int r = 0; r < 4; ++r) {
                const float p = __expf(sc[c][r]);
                l_r[r] += p;
                Ps[w][quad * 4 + r][c * 16 + l16] = f2b_hw(p);
              }
          }

          // PV: O[16q x 64d] += P[16q x 64k] * V[64k x 64d]
          const bf16x8 ap0 = *(const bf16x8*)&Ps[w][l16][quad * 8];
          const bf16x8 ap1 = *(const bf16x8*)&Ps[w][l16][32 + quad * 8];
#pragma unroll
          for (int c = 0; c < 4; ++c) {
            const bf16x8 v0 = *(const bf16x8*)&Vh[hh][c * 16 + l16][quad * 8];
            const bf16x8 v1 = *(const bf16x8*)&Vh[hh][c * 16 + l16][32 + quad * 8];
            O[c] = __builtin_amdgcn_mfma_f32_16x16x32_bf16(ap0, v0, O[c], 0, 0, 0);
            O[c] = __builtin_amdgcn_mfma_f32_16x16x32_bf16(ap1, v1, O[c], 0, 0, 0);
          }
        }
      }
    }

    // epilogue: reduce l, divide, store PACKED (A-fragment layout for out-proj)
#pragma unroll
    for (int r = 0; r < 4; ++r) {
      float l = l_r[r];
#pragma unroll
      for (int off = 1; off < 16; off <<= 1) l += __shfl_xor(l, off, 64);
      const float inv = 1.f / fmaxf(l, 1e-30f);
      const int qg = r0 + w * 16 + quad * 4 + r;
      const int m64 = qg >> 6, t = (qg >> 4) & 3, ql = qg & 15;
#pragma unroll
      for (int c = 0; c < 4; ++c) {
        const int col = h * 64 + c * 16 + l16;
        const int kt = col >> 5, qd = (col >> 3) & 3, j = col & 7;
        attnbuf[((((size_t)m64 * 64 + kt) * 4 + t) * 64 + qd * 16 + ql) * 8 + j] =
            f2b(O[c][r] * inv);
      }
    }
  }
}

// ---------------------------------------------------------------------------
extern "C" void kernel_launch(void* const* d_in, const int* in_sizes, int n_in,
                              void* d_out, int out_size, void* d_ws, size_t ws_size,
                              hipStream_t stream) {
  const float* x    = (const float*)d_in[0];
  const float* Wq   = (const float*)d_in[1];
  const float* Wk   = (const float*)d_in[2];
  const float* Wv   = (const float*)d_in[3];
  const float* Wo   = (const float*)d_in[4];
  const float* cosb = (const float*)d_in[5];
  const float* sinb = (const float*)d_in[6];
  // d_in[7] = attn_mask (causal, applied structurally); d_in[8] = last_pos (=S)
  float* out = (float*)d_out;

  u16* ws      = (u16*)d_ws;
  u16* qkv     = ws;                          // 2048x3072 bf16 (Q 2^-3+roped, K roped)
  u16* attnbuf = ws + 6291456;                // 2048x2048 bf16, PACKED frag layout
  u16* xp      = ws + 10485760;               // x packed (4.2M)
  u16* wqkvp   = ws + 14680064;               // Wq|Wk|Wv packed (6.3M)
  u16* wop     = ws + 20971520;               // Wo packed (4.2M)
  u16* vtg     = ws + 25165824;               // V^T per kv head (512x2048)

  // 1) cast + fragment-pack inputs
  cast_pack_kernel<<<7168, 256, 0, stream>>>(x, Wq, Wk, Wv, Wo, xp, wqkvp, wop);

  // 2) QKV projection (flatmm) + fused RoPE/Q-scale + fused V-transpose
  gemm_flat<0><<<dim3(24, 16), 256, 0, stream>>>(
      xp, wqkvp, qkv, 3072, cosb, sinb, vtg);

  // 3) causal MFMA flash attention: 16 balanced tile-pairs x 32 heads
  attn_kernel<<<dim3(16, 32), 256, 0, stream>>>(qkv, vtg, attnbuf);

  // 4) output projection (flatmm, f32 out)
  gemm_flat<1><<<dim3(16, 16), 256, 0, stream>>>(
      attnbuf, wop, out, 2048, cosb, sinb, vtg);
}

// Round 13
// 243.557 us; speedup vs baseline: 1.0762x; 1.0762x over previous
//
#include <hip/hip_runtime.h>
#include <stdint.h>

typedef unsigned short u16;
typedef unsigned int   u32;

typedef __bf16 bf16x8 __attribute__((ext_vector_type(8)));
typedef float  fx4    __attribute__((ext_vector_type(4)));
typedef u16    u16x8  __attribute__((ext_vector_type(8)));
typedef u16    u16x4  __attribute__((ext_vector_type(4)));

typedef __attribute__((address_space(1))) unsigned int as1_u32;
typedef __attribute__((address_space(3))) unsigned int as3_u32;

// async global->LDS, 16B per lane. LDS dest is wave-uniform base + lane*16.
__device__ __forceinline__ void gload_lds16(const void* g, void* lds) {
  __builtin_amdgcn_global_load_lds((const as1_u32*)(uintptr_t)g,
                                   (as3_u32*)(uintptr_t)lds, 16, 0, 0);
}

__device__ __forceinline__ float b2f(u32 bits) {
  union { u32 i; float f; } v; v.i = bits << 16; return v.f;
}
__device__ __forceinline__ u16 f2b(float f) {
  union { float f; u32 i; } v; v.f = f;
  u32 x = v.i;
  return (u16)((x + 0x7fffu + ((x >> 16) & 1u)) >> 16);  // RNE (sw)
}
__device__ __forceinline__ u16 f2b_hw(float f) {
  union { __bf16 b; u16 u; } v; v.b = (__bf16)f; return v.u;
}

// ---------------------------------------------------------------------------
// Cast f32 -> bf16 for x, Wq, Wk, Wv, Wo into contiguous ws regions (r11).
// ---------------------------------------------------------------------------
__global__ __launch_bounds__(256) void cast_kernel(
    const float* __restrict__ s0, const float* __restrict__ s1,
    const float* __restrict__ s2, const float* __restrict__ s3,
    const float* __restrict__ s4, u16* __restrict__ dst)
{
  const size_t i8 = ((size_t)blockIdx.x * 256 + threadIdx.x) * 8;
  if (i8 >= 14680064) return;
  const float* src; size_t off;
  if      (i8 <  4194304) { src = s0; off = i8; }
  else if (i8 <  8388608) { src = s1; off = i8 - 4194304; }
  else if (i8 <  9437184) { src = s2; off = i8 - 8388608; }
  else if (i8 < 10485760) { src = s3; off = i8 - 9437184; }
  else                    { src = s4; off = i8 - 10485760; }
  const float4 a = *(const float4*)(src + off);
  const float4 b = *(const float4*)(src + off + 4);
  u16x8 o;
  o[0] = f2b(a.x); o[1] = f2b(a.y); o[2] = f2b(a.z); o[3] = f2b(a.w);
  o[4] = f2b(b.x); o[5] = f2b(b.y); o[6] = f2b(b.z); o[7] = f2b(b.w);
  *(u16x8*)(dst + i8) = o;
}

// ---------------------------------------------------------------------------
// Wave-private barrier-free bf16 MFMA GEMM: C[M,N] = A[M,K]*B[N,K]^T.
// Block = 4 waves = 2x2 of 64x64 (128x128/block). EACH WAVE stages its own
// 64x32 A-tile and B-tile into private LDS double buffers via global_load_lds
// (DMA path, no VGPR round-trip) and synchronizes ONLY with its own
// s_waitcnt vmcnt(8). ZERO s_barrier in the kernel: no cross-wave coupling,
// no vmcnt(0) drains (the structural stall of every barriered variant:
// 2-buf=3-buf=4-buf all ~neutral, m131-m141 pattern; r12's flatmm showed
// barrier-free works but lost the DMA path + reuse -- this keeps both).
// Hazards: DMA->ds_read ordered by vmcnt(8) (stage kt's 8 loads are the
// oldest; m97 precedent for LDS visibility via vmcnt). ds_read->DMA-overwrite
// ordered by program order: the MFMAs consuming buf X issue before the next
// stage into X, and mfma issue requires lgkm drain of its operand reads.
// Cost: 2x staging traffic (A,B each staged twice per block) -- absorbed by
// L2 (~750MB @34.5TB/s = 22us floor) and LDS write BW (~116B/cyc/CU < 256).
// MODE 0: QKV epilogue -- RoPE fused (Q pre-scaled 2^-3), V transposed to vt.
// MODE 1: plain f32 store (output projection).
// ---------------------------------------------------------------------------
template <int MODE>
__global__ __launch_bounds__(256) void gemm_wp(
    const u16* __restrict__ A, const u16* __restrict__ B0,
    const u16* __restrict__ B1, const u16* __restrict__ B2,
    void* __restrict__ Cv, int K, int split1, int split2, int ldc,
    const float* __restrict__ cosb, const float* __restrict__ sinb,
    u16* __restrict__ vtg)
{
  __shared__ __align__(16) u16 smem[4][2][4096];  // [wave][buf][A 2048|B 2048]

  const int n0 = blockIdx.x * 128;
  const int m0 = blockIdx.y * 128;

  const u16* Bsel; int nb;
  if (n0 < split1)      { Bsel = B0; nb = n0; }
  else if (n0 < split2) { Bsel = B1; nb = n0 - split1; }
  else                  { Bsel = B2; nb = n0 - split2; }

  const int tid  = threadIdx.x;
  const int wave = tid >> 6, lane = tid & 63;
  const int wm = wave >> 1, wn = wave & 1;
  const int quad = lane >> 4, l16 = lane & 15;

  const int am = m0 + wm * 64;         // wave's A row base (global)
  const int bn = nb + wn * 64;         // wave's B row base (within Bsel)

  // staging coords: inst i covers rows i*16+(lane>>2), cols (lane&3)*8..+8;
  // LDS offset lane*8 elems = row-major (row&15)*32+(col) within the 16-row
  // chunk => contiguous wave-uniform base + lane*16B (DMA requirement).
  const int srow = lane >> 2;
  const int scol = (lane & 3) * 8;

  auto stage = [&](int kt, int b) {
    const int k0 = kt * 32;
    u16* dA = &smem[wave][b][0];
    u16* dB = &smem[wave][b][2048];
#pragma unroll
    for (int i = 0; i < 4; ++i) {
      gload_lds16(A    + (size_t)(am + i * 16 + srow) * K + k0 + scol,
                  dA + i * 512 + lane * 8);
      gload_lds16(Bsel + (size_t)(bn + i * 16 + srow) * K + k0 + scol,
                  dB + i * 512 + lane * 8);
    }
  };

  fx4 acc[4][4];
#pragma unroll
  for (int i = 0; i < 4; ++i)
#pragma unroll
    for (int j = 0; j < 4; ++j) acc[i][j] = fx4{0.f, 0.f, 0.f, 0.f};

  const int KT = K >> 5;               // = 64 for all our shapes
  stage(0, 0);

#pragma unroll 1
  for (int kt = 0; kt < KT; ++kt) {
    if (kt + 1 < KT) {
      stage(kt + 1, (kt + 1) & 1);     // 8 new loads in flight
      // oldest 8 (stage kt) must have landed in LDS before we ds_read them
      asm volatile("s_waitcnt vmcnt(8)" ::: "memory");
    } else {
      asm volatile("s_waitcnt vmcnt(0)" ::: "memory");
    }

    const u16* Asw = &smem[wave][kt & 1][0];
    const u16* Bsw = &smem[wave][kt & 1][2048];
    bf16x8 af[4], bfr[4];
#pragma unroll
    for (int t = 0; t < 4; ++t) {
      af[t]  = *(const bf16x8*)&Asw[(t * 16 + l16) * 32 + quad * 8];
      bfr[t] = *(const bf16x8*)&Bsw[(t * 16 + l16) * 32 + quad * 8];
    }
#pragma unroll
    for (int ti = 0; ti < 4; ++ti)
#pragma unroll
      for (int tj = 0; tj < 4; ++tj)
        acc[ti][tj] = __builtin_amdgcn_mfma_f32_16x16x32_bf16(
            af[ti], bfr[tj], acc[ti][tj], 0, 0, 0);
  }

  if (MODE == 1) {                     // plain f32 store (out-proj)
    float* C = (float*)Cv;
#pragma unroll
    for (int ti = 0; ti < 4; ++ti) {
      const int row_b = m0 + wm * 64 + ti * 16 + quad * 4;
#pragma unroll
      for (int tj = 0; tj < 4; ++tj) {
        const int col = n0 + wn * 64 + tj * 16 + l16;
#pragma unroll
        for (int r = 0; r < 4; ++r)
          C[(size_t)(row_b + r) * ldc + col] = acc[ti][tj][r];
      }
    }
  } else {                             // QKV epilogue
    u16* C = (u16*)Cv;
    const int cb = n0 + wn * 64;       // wave's 64-col span = one head block
    if (cb < 2560) {                   // Q or K: fuse RoPE (+2^-3 scale for Q)
      const float qs = (cb < 2048) ? 0.125f : 1.0f;
#pragma unroll
      for (int ti = 0; ti < 4; ++ti) {
#pragma unroll
        for (int r = 0; r < 4; ++r) {
          const int s = m0 + wm * 64 + ti * 16 + quad * 4 + r;
          const float* cr = cosb + s * 64;
          const float* sr = sinb + s * 64;
          u16* orow = C + (size_t)s * 3072 + cb;
#pragma unroll
          for (int tj = 0; tj < 2; ++tj) {
            const int d0 = tj * 16 + l16, d1 = d0 + 32;
            const float x0 = acc[ti][tj][r], x1 = acc[ti][tj + 2][r];
            orow[d0] = f2b((x0 * cr[d0] - x1 * sr[d0]) * qs);
            orow[d1] = f2b((x1 * cr[d1] + x0 * sr[d1]) * qs);
          }
        }
      }
    } else {                           // V: store TRANSPOSED to vt[d][key]
      const int vr0 = cb - 2560;
#pragma unroll
      for (int ti = 0; ti < 4; ++ti) {
        const int s0 = m0 + wm * 64 + ti * 16 + quad * 4;
#pragma unroll
        for (int tj = 0; tj < 4; ++tj) {
          const int vr = vr0 + tj * 16 + l16;
          u16x4 o;
#pragma unroll
          for (int r = 0; r < 4; ++r) o[r] = f2b(acc[ti][tj][r]);
          *(u16x4*)(vtg + (size_t)vr * 2048 + s0) = o;
        }
      }
    }
  }
}

// ---------------------------------------------------------------------------
// MFMA causal flash attention (r11, byte-identical). Block = head h + TWO
// q-tiles (b and 31-b) = exactly 17 staging iters. Sync staging, 128-key
// tiles. Exact shift-by-0 softmax; hw bf16 cvt; diagonal-only mask.
// ---------------------------------------------------------------------------
__global__ __launch_bounds__(256) void attn_kernel(
    const u16* __restrict__ qkv, const u16* __restrict__ vt,
    u16* __restrict__ attnbuf)
{
  const int h   = blockIdx.y;
  const int kvh = h >> 2;                  // GQA group = 4
  const int tid = threadIdx.x;
  const int w = tid >> 6, lane = tid & 63;
  const int quad = lane >> 4, l16 = lane & 15;

  __shared__ __align__(16) u16 Qs[64][72];
  __shared__ __align__(16) u16 Ks[128][72];
  __shared__ __align__(16) u16 Vh[2][64][72];
  __shared__ __align__(16) u16 Ps[4][16][72];

  const int kcol = 2048 + kvh * 64;

#pragma unroll 1
  for (int pass = 0; pass < 2; ++pass) {
    const int bx = pass ? (31 - blockIdx.x) : blockIdx.x;
    const int r0 = bx * 64;
    const int nhalf  = bx + 1;           // 64-key halves to process
    const int ntiles = (bx + 2) >> 1;    // 128-key tiles to stage

    __syncthreads();                     // prev pass's LDS reads done

    // stage Q (already 2^-3-scaled by the QKV epilogue)
#pragma unroll
    for (int i = 0; i < 2; ++i) {
      const int idx = tid + i * 256;
      const int r = idx >> 3, dc = (idx & 7) * 8;
      *(uint4*)&Qs[r][dc] =
          *(const uint4*)(qkv + (size_t)(r0 + r) * 3072 + h * 64 + dc);
    }

    fx4 O[4];
    float l_r[4];
#pragma unroll
    for (int c = 0; c < 4; ++c) O[c] = fx4{0.f, 0.f, 0.f, 0.f};
#pragma unroll
    for (int r = 0; r < 4; ++r) l_r[r] = 0.f;

#pragma unroll 1
    for (int kt = 0; kt < ntiles; ++kt) {
      const int k0 = kt * 128;
      __syncthreads();                   // prev stage's LDS reads done
#pragma unroll
      for (int i = 0; i < 4; ++i) {      // stage K 128x64
        const int idx = tid + i * 256;
        const int j = idx >> 3, dc = (idx & 7) * 8;
        *(uint4*)&Ks[j][dc] =
            *(const uint4*)(qkv + (size_t)(k0 + j) * 3072 + kcol + dc);
      }
#pragma unroll
      for (int i = 0; i < 4; ++i) {      // stage V^T as two 64x64 halves
        const int idx = tid + i * 256;
        const int hh = idx >> 9, rem = idx & 511;
        const int j = rem >> 3, dc = (rem & 7) * 8;
        *(uint4*)&Vh[hh][j][dc] =
            *(const uint4*)(vt + (size_t)(kvh * 64 + j) * 2048 + k0 + hh * 64 + dc);
      }
      __syncthreads();                   // publish (one drain / 128 keys)

      const bf16x8 aq0 = *(const bf16x8*)&Qs[w * 16 + l16][quad * 8];
      const bf16x8 aq1 = *(const bf16x8*)&Qs[w * 16 + l16][32 + quad * 8];

#pragma unroll
      for (int hh = 0; hh < 2; ++hh) {
        const int half = kt * 2 + hh;
        if (half < nhalf) {
          const int k0h = k0 + hh * 64;

          fx4 sc[4];
#pragma unroll
          for (int c = 0; c < 4; ++c) {
            const bf16x8 b0 = *(const bf16x8*)&Ks[hh * 64 + c * 16 + l16][quad * 8];
            const bf16x8 b1 = *(const bf16x8*)&Ks[hh * 64 + c * 16 + l16][32 + quad * 8];
            fx4 z = fx4{0.f, 0.f, 0.f, 0.f};
            z     = __builtin_amdgcn_mfma_f32_16x16x32_bf16(aq0, b0, z, 0, 0, 0);
            sc[c] = __builtin_amdgcn_mfma_f32_16x16x32_bf16(aq1, b1, z, 0, 0, 0);
          }

          if (k0h >= r0) {               // diagonal half: masked exp
#pragma unroll
            for (int c = 0; c < 4; ++c)
#pragma unroll
              for (int r = 0; r < 4; ++r) {
                float p = __expf(sc[c][r]);
                if (k0h + c * 16 + l16 > r0 + w * 16 + quad * 4 + r) p = 0.f;
                l_r[r] += p;
                Ps[w][quad * 4 + r][c * 16 + l16] = f2b_hw(p);
              }
          } else {                       // interior half: plain exp
#pragma unroll
            for (int c = 0; c < 4; ++c)
#pragma unroll
              for (int r = 0; r < 4; ++r) {
                const float p = __expf(sc[c][r]);
                l_r[r] += p;
                Ps[w][quad * 4 + r][c * 16 + l16] = f2b_hw(p);
              }
          }

          const bf16x8 ap0 = *(const bf16x8*)&Ps[w][l16][quad * 8];
          const bf16x8 ap1 = *(const bf16x8*)&Ps[w][l16][32 + quad * 8];
#pragma unroll
          for (int c = 0; c < 4; ++c) {
            const bf16x8 v0 = *(const bf16x8*)&Vh[hh][c * 16 + l16][quad * 8];
            const bf16x8 v1 = *(const bf16x8*)&Vh[hh][c * 16 + l16][32 + quad * 8];
            O[c] = __builtin_amdgcn_mfma_f32_16x16x32_bf16(ap0, v0, O[c], 0, 0, 0);
            O[c] = __builtin_amdgcn_mfma_f32_16x16x32_bf16(ap1, v1, O[c], 0, 0, 0);
          }
        }
      }
    }

    // epilogue: reduce l across the 16 lanes of the quad, divide, store
#pragma unroll
    for (int r = 0; r < 4; ++r) {
      float l = l_r[r];
#pragma unroll
      for (int off = 1; off < 16; off <<= 1) l += __shfl_xor(l, off, 64);
      const float inv = 1.f / fmaxf(l, 1e-30f);
      const int qg = r0 + w * 16 + quad * 4 + r;
#pragma unroll
      for (int c = 0; c < 4; ++c)
        attnbuf[(size_t)qg * 2048 + h * 64 + c * 16 + l16] = f2b(O[c][r] * inv);
    }
  }
}

// ---------------------------------------------------------------------------
extern "C" void kernel_launch(void* const* d_in, const int* in_sizes, int n_in,
                              void* d_out, int out_size, void* d_ws, size_t ws_size,
                              hipStream_t stream) {
  const float* x    = (const float*)d_in[0];
  const float* Wq   = (const float*)d_in[1];
  const float* Wk   = (const float*)d_in[2];
  const float* Wv   = (const float*)d_in[3];
  const float* Wo   = (const float*)d_in[4];
  const float* cosb = (const float*)d_in[5];
  const float* sinb = (const float*)d_in[6];
  // d_in[7] = attn_mask (causal, applied structurally); d_in[8] = last_pos (=S)
  float* out = (float*)d_out;

  u16* ws      = (u16*)d_ws;
  u16* qkv     = ws;                          // 2048x3072 bf16 (Q 2^-3+roped, K roped)
  u16* attnbuf = ws + 6291456;                // 2048x2048 bf16
  u16* xb      = ws + 10485760;               // 2048x2048 bf16
  u16* Wqb     = ws + 14680064;               // 2048x2048
  u16* Wkb     = ws + 18874368;               //  512x2048
  u16* Wvb     = ws + 19922944;               //  512x2048
  u16* Wob     = ws + 20971520;               // 2048x2048
  u16* vtg     = ws + 25165824;               //  512x2048 (V^T per kv head)

  // 1) cast inputs to bf16
  cast_kernel<<<7168, 256, 0, stream>>>(x, Wq, Wk, Wv, Wo, xb);

  // 2) QKV projection + fused RoPE/Q-scale + fused V-transpose
  gemm_wp<0><<<dim3(24, 16), 256, 0, stream>>>(
      xb, Wqb, Wkb, Wvb, qkv, 2048, 2048, 2560, 3072, cosb, sinb, vtg);

  // 3) causal MFMA flash attention: 16 balanced tile-pairs x 32 heads
  attn_kernel<<<dim3(16, 32), 256, 0, stream>>>(qkv, vtg, attnbuf);

  // 4) output projection (f32 out)
  gemm_wp<1><<<dim3(16, 16), 256, 0, stream>>>(
      attnbuf, Wob, Wob, Wob, out, 2048, 1 << 30, 1 << 30, 2048, cosb, sinb, vtg);
}

// Round 14
// 237.796 us; speedup vs baseline: 1.1022x; 1.0242x over previous
//
#include <hip/hip_runtime.h>
#include <stdint.h>

typedef unsigned short u16;
typedef unsigned int   u32;

typedef __bf16 bf16x8 __attribute__((ext_vector_type(8)));
typedef float  fx4    __attribute__((ext_vector_type(4)));
typedef u16    u16x8  __attribute__((ext_vector_type(8)));
typedef u16    u16x4  __attribute__((ext_vector_type(4)));

typedef __attribute__((address_space(1))) unsigned int as1_u32;
typedef __attribute__((address_space(3))) unsigned int as3_u32;

// async global->LDS, 16B per lane. LDS dest is wave-uniform base + lane*16.
__device__ __forceinline__ void gload_lds16(const void* g, void* lds) {
  __builtin_amdgcn_global_load_lds((const as1_u32*)(uintptr_t)g,
                                   (as3_u32*)(uintptr_t)lds, 16, 0, 0);
}

__device__ __forceinline__ float b2f(u32 bits) {
  union { u32 i; float f; } v; v.i = bits << 16; return v.f;
}
__device__ __forceinline__ u16 f2b(float f) {
  union { float f; u32 i; } v; v.f = f;
  u32 x = v.i;
  return (u16)((x + 0x7fffu + ((x >> 16) & 1u)) >> 16);  // RNE (sw)
}
__device__ __forceinline__ u16 f2b_hw(float f) {
  union { __bf16 b; u16 u; } v; v.b = (__bf16)f; return v.u;
}

// ---------------------------------------------------------------------------
// Cast f32 -> bf16 for x, Wq, Wk, Wv, Wo into contiguous ws regions.
// ---------------------------------------------------------------------------
__global__ __launch_bounds__(256) void cast_kernel(
    const float* __restrict__ s0, const float* __restrict__ s1,
    const float* __restrict__ s2, const float* __restrict__ s3,
    const float* __restrict__ s4, u16* __restrict__ dst)
{
  const size_t i8 = ((size_t)blockIdx.x * 256 + threadIdx.x) * 8;
  if (i8 >= 14680064) return;
  const float* src; size_t off;
  if      (i8 <  4194304) { src = s0; off = i8; }
  else if (i8 <  8388608) { src = s1; off = i8 - 4194304; }
  else if (i8 <  9437184) { src = s2; off = i8 - 8388608; }
  else if (i8 < 10485760) { src = s3; off = i8 - 9437184; }
  else                    { src = s4; off = i8 - 10485760; }
  const float4 a = *(const float4*)(src + off);
  const float4 b = *(const float4*)(src + off + 4);
  u16x8 o;
  o[0] = f2b(a.x); o[1] = f2b(a.y); o[2] = f2b(a.z); o[3] = f2b(a.w);
  o[4] = f2b(b.x); o[5] = f2b(b.y); o[6] = f2b(b.z); o[7] = f2b(b.w);
  *(u16x8*)(dst + i8) = o;
}

// ---------------------------------------------------------------------------
// bf16 MFMA GEMM, 64x128 block tile (ROUND-14). Every barriered pipeline
// variant at 128x128 (2-buf/3-buf/4-buf/wave-private) left the GEMM at
// ~55-60us because the grid gave only 1-1.5 blocks/CU -- the regime where
// cross-wave overlap can't hide staging latency (m99/m114: ~3 blocks/CU is
// where implicit overlap works). Halving the M-tile doubles the grid:
// QKV 768 blocks (3/CU), outproj 512 (2/CU). 4 waves as 2x2 of 32x64;
// wave n-span stays 64 = one head, preserving the verified RoPE/V epilogues.
// 3-buf, 2-ahead async global_load_lds pipeline, fine vmcnt(3), raw barriers.
// LDS 3 x (A 4KB + B 8KB) = 36KB. acc = 8 fx4 = 32 VGPR.
// MODE 0: QKV epilogue -- fused RoPE (Q pre-scaled 2^-3), V transposed to vt.
// MODE 1: plain f32 store (output projection).
// ---------------------------------------------------------------------------
template <int MODE>
__global__ __launch_bounds__(256) void gemm_bt(
    const u16* __restrict__ A, const u16* __restrict__ B0,
    const u16* __restrict__ B1, const u16* __restrict__ B2,
    void* __restrict__ Cv, int K, int split1, int split2, int ldc,
    const float* __restrict__ cosb, const float* __restrict__ sinb,
    u16* __restrict__ vtg)
{
  __shared__ __align__(16) u16 smem[3][6144];   // [buf][A 2048 | B 4096]

  const int n0 = blockIdx.x * 128;
  const int m0 = blockIdx.y * 64;

  const u16* Bsel; int nb;
  if (n0 < split1)      { Bsel = B0; nb = n0; }
  else if (n0 < split2) { Bsel = B1; nb = n0 - split1; }
  else                  { Bsel = B2; nb = n0 - split2; }

  const int tid  = threadIdx.x;
  const int wave = tid >> 6, lane = tid & 63;
  const int wm = wave >> 1, wn = wave & 1;      // 2x2 waves of 32(M) x 64(N)
  const int quad = lane >> 4, l16 = lane & 15;

  fx4 acc[2][4];
#pragma unroll
  for (int i = 0; i < 2; ++i)
#pragma unroll
    for (int j = 0; j < 4; ++j) acc[i][j] = fx4{0.f, 0.f, 0.f, 0.f};

  auto stage = [&](int kt, int b) {
    u16* As = &smem[b][0];
    u16* Bs = &smem[b][2048];
    const int k0 = kt * 32;
    {   // A: 64 rows x 32 cols = 256 x 16B chunks, 1 per thread
      const int row = tid >> 2, c = (tid & 3) * 8;
      gload_lds16(A + (size_t)(m0 + row) * K + k0 + c, As + tid * 8);
    }
#pragma unroll
    for (int i = 0; i < 2; ++i) {   // B: 128 rows = 512 chunks, 2 per thread
      const int s = tid + i * 256;
      const int row = s >> 2, c = (s & 3) * 8;
      gload_lds16(Bsel + (size_t)(nb + row) * K + k0 + c, Bs + s * 8);
    }
  };

  const int KT = K >> 5;               // = 64 for all our shapes
  stage(0, 0);
  stage(1, 1);

#pragma unroll 1
  for (int kt = 0; kt < KT; ++kt) {
    // 3 gloads per thread per stage; wait until stage kt's (oldest 3) landed,
    // keep stage kt+1's 3 in flight. Raw barrier: no vmcnt(0) drain.
    if (kt < KT - 1) asm volatile("s_waitcnt vmcnt(3)\n\ts_barrier" ::: "memory");
    else             asm volatile("s_waitcnt vmcnt(0)\n\ts_barrier" ::: "memory");
    if (kt + 2 < KT) stage(kt + 2, (kt + 2) % 3);

    const u16* As = &smem[kt % 3][0];
    const u16* Bs = &smem[kt % 3][2048];

    bf16x8 af[2], bfr[4];
#pragma unroll
    for (int t = 0; t < 2; ++t)
      af[t]  = *(const bf16x8*)&As[(wm * 32 + t * 16 + l16) * 32 + quad * 8];
#pragma unroll
    for (int t = 0; t < 4; ++t)
      bfr[t] = *(const bf16x8*)&Bs[(wn * 64 + t * 16 + l16) * 32 + quad * 8];
#pragma unroll
    for (int ti = 0; ti < 2; ++ti)
#pragma unroll
      for (int tj = 0; tj < 4; ++tj)
        acc[ti][tj] = __builtin_amdgcn_mfma_f32_16x16x32_bf16(
            af[ti], bfr[tj], acc[ti][tj], 0, 0, 0);
  }

  if (MODE == 1) {                     // plain f32 store (out-proj)
    float* C = (float*)Cv;
#pragma unroll
    for (int ti = 0; ti < 2; ++ti) {
      const int row_b = m0 + wm * 32 + ti * 16 + quad * 4;
#pragma unroll
      for (int tj = 0; tj < 4; ++tj) {
        const int col = n0 + wn * 64 + tj * 16 + l16;
#pragma unroll
        for (int r = 0; r < 4; ++r)
          C[(size_t)(row_b + r) * ldc + col] = acc[ti][tj][r];
      }
    }
  } else {                             // QKV epilogue
    u16* C = (u16*)Cv;
    const int cb = n0 + wn * 64;       // wave's 64-col span = one head block
    if (cb < 2560) {                   // Q or K: fuse RoPE (+2^-3 scale for Q)
      const float qs = (cb < 2048) ? 0.125f : 1.0f;
#pragma unroll
      for (int ti = 0; ti < 2; ++ti) {
#pragma unroll
        for (int r = 0; r < 4; ++r) {
          const int s = m0 + wm * 32 + ti * 16 + quad * 4 + r;
          const float* cr = cosb + s * 64;
          const float* sr = sinb + s * 64;
          u16* orow = C + (size_t)s * 3072 + cb;
#pragma unroll
          for (int tj = 0; tj < 2; ++tj) {
            const int d0 = tj * 16 + l16, d1 = d0 + 32;
            const float x0 = acc[ti][tj][r], x1 = acc[ti][tj + 2][r];
            orow[d0] = f2b((x0 * cr[d0] - x1 * sr[d0]) * qs);
            orow[d1] = f2b((x1 * cr[d1] + x0 * sr[d1]) * qs);
          }
        }
      }
    } else {                           // V: store TRANSPOSED to vt[d][key]
      const int vr0 = cb - 2560;
#pragma unroll
      for (int ti = 0; ti < 2; ++ti) {
        const int s0 = m0 + wm * 32 + ti * 16 + quad * 4;
#pragma unroll
        for (int tj = 0; tj < 4; ++tj) {
          const int vr = vr0 + tj * 16 + l16;
          u16x4 o;
#pragma unroll
          for (int r = 0; r < 4; ++r) o[r] = f2b(acc[ti][tj][r]);
          *(u16x4*)(vtg + (size_t)vr * 2048 + s0) = o;
        }
      }
    }
  }
}

// ---------------------------------------------------------------------------
// MFMA causal flash attention (r11, byte-identical). Block = head h + TWO
// q-tiles (b and 31-b) = exactly 17 staging iters. Sync staging, 128-key
// tiles. Exact shift-by-0 softmax; hw bf16 cvt; diagonal-only mask.
// ---------------------------------------------------------------------------
__global__ __launch_bounds__(256) void attn_kernel(
    const u16* __restrict__ qkv, const u16* __restrict__ vt,
    u16* __restrict__ attnbuf)
{
  const int h   = blockIdx.y;
  const int kvh = h >> 2;                  // GQA group = 4
  const int tid = threadIdx.x;
  const int w = tid >> 6, lane = tid & 63;
  const int quad = lane >> 4, l16 = lane & 15;

  __shared__ __align__(16) u16 Qs[64][72];
  __shared__ __align__(16) u16 Ks[128][72];
  __shared__ __align__(16) u16 Vh[2][64][72];
  __shared__ __align__(16) u16 Ps[4][16][72];

  const int kcol = 2048 + kvh * 64;

#pragma unroll 1
  for (int pass = 0; pass < 2; ++pass) {
    const int bx = pass ? (31 - blockIdx.x) : blockIdx.x;
    const int r0 = bx * 64;
    const int nhalf  = bx + 1;           // 64-key halves to process
    const int ntiles = (bx + 2) >> 1;    // 128-key tiles to stage

    __syncthreads();                     // prev pass's LDS reads done

    // stage Q (already 2^-3-scaled by the QKV epilogue)
#pragma unroll
    for (int i = 0; i < 2; ++i) {
      const int idx = tid + i * 256;
      const int r = idx >> 3, dc = (idx & 7) * 8;
      *(uint4*)&Qs[r][dc] =
          *(const uint4*)(qkv + (size_t)(r0 + r) * 3072 + h * 64 + dc);
    }

    fx4 O[4];
    float l_r[4];
#pragma unroll
    for (int c = 0; c < 4; ++c) O[c] = fx4{0.f, 0.f, 0.f, 0.f};
#pragma unroll
    for (int r = 0; r < 4; ++r) l_r[r] = 0.f;

#pragma unroll 1
    for (int kt = 0; kt < ntiles; ++kt) {
      const int k0 = kt * 128;
      __syncthreads();                   // prev stage's LDS reads done
#pragma unroll
      for (int i = 0; i < 4; ++i) {      // stage K 128x64
        const int idx = tid + i * 256;
        const int j = idx >> 3, dc = (idx & 7) * 8;
        *(uint4*)&Ks[j][dc] =
            *(const uint4*)(qkv + (size_t)(k0 + j) * 3072 + kcol + dc);
      }
#pragma unroll
      for (int i = 0; i < 4; ++i) {      // stage V^T as two 64x64 halves
        const int idx = tid + i * 256;
        const int hh = idx >> 9, rem = idx & 511;
        const int j = rem >> 3, dc = (rem & 7) * 8;
        *(uint4*)&Vh[hh][j][dc] =
            *(const uint4*)(vt + (size_t)(kvh * 64 + j) * 2048 + k0 + hh * 64 + dc);
      }
      __syncthreads();                   // publish (one drain / 128 keys)

      const bf16x8 aq0 = *(const bf16x8*)&Qs[w * 16 + l16][quad * 8];
      const bf16x8 aq1 = *(const bf16x8*)&Qs[w * 16 + l16][32 + quad * 8];

#pragma unroll
      for (int hh = 0; hh < 2; ++hh) {
        const int half = kt * 2 + hh;
        if (half < nhalf) {
          const int k0h = k0 + hh * 64;

          fx4 sc[4];
#pragma unroll
          for (int c = 0; c < 4; ++c) {
            const bf16x8 b0 = *(const bf16x8*)&Ks[hh * 64 + c * 16 + l16][quad * 8];
            const bf16x8 b1 = *(const bf16x8*)&Ks[hh * 64 + c * 16 + l16][32 + quad * 8];
            fx4 z = fx4{0.f, 0.f, 0.f, 0.f};
            z     = __builtin_amdgcn_mfma_f32_16x16x32_bf16(aq0, b0, z, 0, 0, 0);
            sc[c] = __builtin_amdgcn_mfma_f32_16x16x32_bf16(aq1, b1, z, 0, 0, 0);
          }

          if (k0h >= r0) {               // diagonal half: masked exp
#pragma unroll
            for (int c = 0; c < 4; ++c)
#pragma unroll
              for (int r = 0; r < 4; ++r) {
                float p = __expf(sc[c][r]);
                if (k0h + c * 16 + l16 > r0 + w * 16 + quad * 4 + r) p = 0.f;
                l_r[r] += p;
                Ps[w][quad * 4 + r][c * 16 + l16] = f2b_hw(p);
              }
          } else {                       // interior half: plain exp
#pragma unroll
            for (int c = 0; c < 4; ++c)
#pragma unroll
              for (int r = 0; r < 4; ++r) {
                const float p = __expf(sc[c][r]);
                l_r[r] += p;
                Ps[w][quad * 4 + r][c * 16 + l16] = f2b_hw(p);
              }
          }

          const bf16x8 ap0 = *(const bf16x8*)&Ps[w][l16][quad * 8];
          const bf16x8 ap1 = *(const bf16x8*)&Ps[w][l16][32 + quad * 8];
#pragma unroll
          for (int c = 0; c < 4; ++c) {
            const bf16x8 v0 = *(const bf16x8*)&Vh[hh][c * 16 + l16][quad * 8];
            const bf16x8 v1 = *(const bf16x8*)&Vh[hh][c * 16 + l16][32 + quad * 8];
            O[c] = __builtin_amdgcn_mfma_f32_16x16x32_bf16(ap0, v0, O[c], 0, 0, 0);
            O[c] = __builtin_amdgcn_mfma_f32_16x16x32_bf16(ap1, v1, O[c], 0, 0, 0);
          }
        }
      }
    }

    // epilogue: reduce l across the 16 lanes of the quad, divide, store
#pragma unroll
    for (int r = 0; r < 4; ++r) {
      float l = l_r[r];
#pragma unroll
      for (int off = 1; off < 16; off <<= 1) l += __shfl_xor(l, off, 64);
      const float inv = 1.f / fmaxf(l, 1e-30f);
      const int qg = r0 + w * 16 + quad * 4 + r;
#pragma unroll
      for (int c = 0; c < 4; ++c)
        attnbuf[(size_t)qg * 2048 + h * 64 + c * 16 + l16] = f2b(O[c][r] * inv);
    }
  }
}

// ---------------------------------------------------------------------------
extern "C" void kernel_launch(void* const* d_in, const int* in_sizes, int n_in,
                              void* d_out, int out_size, void* d_ws, size_t ws_size,
                              hipStream_t stream) {
  const float* x    = (const float*)d_in[0];
  const float* Wq   = (const float*)d_in[1];
  const float* Wk   = (const float*)d_in[2];
  const float* Wv   = (const float*)d_in[3];
  const float* Wo   = (const float*)d_in[4];
  const float* cosb = (const float*)d_in[5];
  const float* sinb = (const float*)d_in[6];
  // d_in[7] = attn_mask (causal, applied structurally); d_in[8] = last_pos (=S)
  float* out = (float*)d_out;

  u16* ws      = (u16*)d_ws;
  u16* qkv     = ws;                          // 2048x3072 bf16 (Q 2^-3+roped, K roped)
  u16* attnbuf = ws + 6291456;                // 2048x2048 bf16
  u16* xb      = ws + 10485760;               // 2048x2048 bf16
  u16* Wqb     = ws + 14680064;               // 2048x2048
  u16* Wkb     = ws + 18874368;               //  512x2048
  u16* Wvb     = ws + 19922944;               //  512x2048
  u16* Wob     = ws + 20971520;               // 2048x2048
  u16* vtg     = ws + 25165824;               //  512x2048 (V^T per kv head)

  // 1) cast inputs to bf16
  cast_kernel<<<7168, 256, 0, stream>>>(x, Wq, Wk, Wv, Wo, xb);

  // 2) QKV projection + fused RoPE/Q-scale + fused V-transpose
  //    64x128 tiles: grid 24x32 = 768 blocks = 3 blocks/CU
  gemm_bt<0><<<dim3(24, 32), 256, 0, stream>>>(
      xb, Wqb, Wkb, Wvb, qkv, 2048, 2048, 2560, 3072, cosb, sinb, vtg);

  // 3) causal MFMA flash attention: 16 balanced tile-pairs x 32 heads
  attn_kernel<<<dim3(16, 32), 256, 0, stream>>>(qkv, vtg, attnbuf);

  // 4) output projection (f32 out): 64x128 tiles, 512 blocks = 2/CU
  gemm_bt<1><<<dim3(16, 32), 256, 0, stream>>>(
      attnbuf, Wob, Wob, Wob, out, 2048, 1 << 30, 1 << 30, 2048, cosb, sinb, vtg);
}

// Round 15
// 235.001 us; speedup vs baseline: 1.1153x; 1.0119x over previous
//
#include <hip/hip_runtime.h>
#include <stdint.h>

typedef unsigned short u16;
typedef unsigned int   u32;

typedef __bf16 bf16x8 __attribute__((ext_vector_type(8)));
typedef float  fx4    __attribute__((ext_vector_type(4)));
typedef u16    u16x8  __attribute__((ext_vector_type(8)));
typedef u16    u16x4  __attribute__((ext_vector_type(4)));

typedef __attribute__((address_space(1))) unsigned int as1_u32;
typedef __attribute__((address_space(3))) unsigned int as3_u32;

// async global->LDS, 16B per lane. LDS dest is wave-uniform base + lane*16.
__device__ __forceinline__ void gload_lds16(const void* g, void* lds) {
  __builtin_amdgcn_global_load_lds((const as1_u32*)(uintptr_t)g,
                                   (as3_u32*)(uintptr_t)lds, 16, 0, 0);
}

__device__ __forceinline__ float b2f(u32 bits) {
  union { u32 i; float f; } v; v.i = bits << 16; return v.f;
}
__device__ __forceinline__ u16 f2b(float f) {
  union { float f; u32 i; } v; v.f = f;
  u32 x = v.i;
  return (u16)((x + 0x7fffu + ((x >> 16) & 1u)) >> 16);  // RNE (sw)
}
__device__ __forceinline__ u16 f2b_hw(float f) {
  union { __bf16 b; u16 u; } v; v.b = (__bf16)f; return v.u;
}

// ---------------------------------------------------------------------------
// Cast f32 -> bf16 for x, Wq, Wk, Wv, Wo into contiguous ws regions.
// ---------------------------------------------------------------------------
__global__ __launch_bounds__(256) void cast_kernel(
    const float* __restrict__ s0, const float* __restrict__ s1,
    const float* __restrict__ s2, const float* __restrict__ s3,
    const float* __restrict__ s4, u16* __restrict__ dst)
{
  const size_t i8 = ((size_t)blockIdx.x * 256 + threadIdx.x) * 8;
  if (i8 >= 14680064) return;
  const float* src; size_t off;
  if      (i8 <  4194304) { src = s0; off = i8; }
  else if (i8 <  8388608) { src = s1; off = i8 - 4194304; }
  else if (i8 <  9437184) { src = s2; off = i8 - 8388608; }
  else if (i8 < 10485760) { src = s3; off = i8 - 9437184; }
  else                    { src = s4; off = i8 - 10485760; }
  const float4 a = *(const float4*)(src + off);
  const float4 b = *(const float4*)(src + off + 4);
  u16x8 o;
  o[0] = f2b(a.x); o[1] = f2b(a.y); o[2] = f2b(a.z); o[3] = f2b(a.w);
  o[4] = f2b(b.x); o[5] = f2b(b.y); o[6] = f2b(b.z); o[7] = f2b(b.w);
  *(u16x8*)(dst + i8) = o;
}

// ---------------------------------------------------------------------------
// bf16 MFMA GEMM (r11 config -- the 229.8us best; GEMM structure exploration
// is closed after 7 variants all landed at 55+-5us, matching the m102 shape
// plateau for 2048-class GEMMs). 128x128 tile, BK=32, 4 waves (2x2 of 64x64).
// 4-buffer, 3-ahead async global_load_lds pipeline, exact tail vmcnt ladder,
// raw barriers (no vmcnt(0) drain mid-loop).
// MODE 0: QKV epilogue -- RoPE fused (Q pre-scaled 2^-3), V transposed to vt.
// MODE 1: plain f32 store (output projection).
// ---------------------------------------------------------------------------
template <int MODE>
__global__ __launch_bounds__(256) void gemm_bt(
    const u16* __restrict__ A, const u16* __restrict__ B0,
    const u16* __restrict__ B1, const u16* __restrict__ B2,
    void* __restrict__ Cv, int K, int split1, int split2, int ldc,
    const float* __restrict__ cosb, const float* __restrict__ sinb,
    u16* __restrict__ vtg)
{
  __shared__ __align__(16) u16 smem[4 * 8192];   // 4 bufs x (A 8KB + B 8KB)

  const int n0 = blockIdx.x * 128;
  const int m0 = blockIdx.y * 128;

  const u16* Bsel; int nb;
  if (n0 < split1)      { Bsel = B0; nb = n0; }
  else if (n0 < split2) { Bsel = B1; nb = n0 - split1; }
  else                  { Bsel = B2; nb = n0 - split2; }

  const int tid  = threadIdx.x;
  const int wave = tid >> 6, lane = tid & 63;
  const int wm = wave >> 1, wn = wave & 1;
  const int quad = lane >> 4, l16 = lane & 15;

  fx4 acc[4][4];
#pragma unroll
  for (int i = 0; i < 4; ++i)
#pragma unroll
    for (int j = 0; j < 4; ++j) acc[i][j] = fx4{0.f, 0.f, 0.f, 0.f};

  const int row = tid >> 2;            // staging coords (4 x 16B per 32-col row)
  const int cc  = (tid & 3) * 8;
  auto stage = [&](int kt) {
    u16* As = smem + (kt & 3) * 8192;
    u16* Bs = As + 4096;
    const int k0 = kt * 32;
#pragma unroll
    for (int i = 0; i < 2; ++i) {
      const int r2 = row + i * 64;
      const int s  = tid + i * 256;
      gload_lds16(A    + (size_t)(m0 + r2) * K + k0 + cc, As + s * 8);
      gload_lds16(Bsel + (size_t)(nb + r2) * K + k0 + cc, Bs + s * 8);
    }
  };

  const int KT = K >> 5;               // = 64 for all our shapes
  stage(0); stage(1); stage(2);

#pragma unroll 1
  for (int kt = 0; kt < KT; ++kt) {
    const int rem = KT - 1 - kt;       // stages in flight after stage kt
    if (rem >= 3)      asm volatile("s_waitcnt vmcnt(12)\n\ts_barrier" ::: "memory");
    else if (rem == 2) asm volatile("s_waitcnt vmcnt(8)\n\ts_barrier" ::: "memory");
    else if (rem == 1) asm volatile("s_waitcnt vmcnt(4)\n\ts_barrier" ::: "memory");
    else               asm volatile("s_waitcnt vmcnt(0)\n\ts_barrier" ::: "memory");
    if (kt + 3 < KT) stage(kt + 3);

    const u16* As = smem + (kt & 3) * 8192;
    const u16* Bs = As + 4096;

    bf16x8 af[4], bfr[4];
#pragma unroll
    for (int t = 0; t < 4; ++t) {
      af[t]  = *(const bf16x8*)&As[(wm * 64 + t * 16 + l16) * 32 + quad * 8];
      bfr[t] = *(const bf16x8*)&Bs[(wn * 64 + t * 16 + l16) * 32 + quad * 8];
    }
#pragma unroll
    for (int ti = 0; ti < 4; ++ti)
#pragma unroll
      for (int tj = 0; tj < 4; ++tj)
        acc[ti][tj] = __builtin_amdgcn_mfma_f32_16x16x32_bf16(
            af[ti], bfr[tj], acc[ti][tj], 0, 0, 0);
  }

  if (MODE == 1) {                     // plain f32 store (out-proj)
    float* C = (float*)Cv;
#pragma unroll
    for (int ti = 0; ti < 4; ++ti) {
      const int row_b = m0 + wm * 64 + ti * 16 + quad * 4;
#pragma unroll
      for (int tj = 0; tj < 4; ++tj) {
        const int col = n0 + wn * 64 + tj * 16 + l16;
#pragma unroll
        for (int r = 0; r < 4; ++r)
          C[(size_t)(row_b + r) * ldc + col] = acc[ti][tj][r];
      }
    }
  } else {                             // QKV epilogue
    u16* C = (u16*)Cv;
    const int cb = n0 + wn * 64;       // wave's 64-col span = one head block
    if (cb < 2560) {                   // Q or K: fuse RoPE (+2^-3 scale for Q)
      const float qs = (cb < 2048) ? 0.125f : 1.0f;
#pragma unroll
      for (int ti = 0; ti < 4; ++ti) {
#pragma unroll
        for (int r = 0; r < 4; ++r) {
          const int s = m0 + wm * 64 + ti * 16 + quad * 4 + r;
          const float* cr = cosb + s * 64;
          const float* sr = sinb + s * 64;
          u16* orow = C + (size_t)s * 3072 + cb;
#pragma unroll
          for (int tj = 0; tj < 2; ++tj) {
            const int d0 = tj * 16 + l16, d1 = d0 + 32;
            const float x0 = acc[ti][tj][r], x1 = acc[ti][tj + 2][r];
            orow[d0] = f2b((x0 * cr[d0] - x1 * sr[d0]) * qs);
            orow[d1] = f2b((x1 * cr[d1] + x0 * sr[d1]) * qs);
          }
        }
      }
    } else {                           // V: store TRANSPOSED to vt[d][key]
      const int vr0 = cb - 2560;
#pragma unroll
      for (int ti = 0; ti < 4; ++ti) {
        const int s0 = m0 + wm * 64 + ti * 16 + quad * 4;
#pragma unroll
        for (int tj = 0; tj < 4; ++tj) {
          const int vr = vr0 + tj * 16 + l16;
          u16x4 o;
#pragma unroll
          for (int r = 0; r < 4; ++r) o[r] = f2b(acc[ti][tj][r]);
          *(u16x4*)(vtg + (size_t)vr * 2048 + s0) = o;
        }
      }
    }
  }
}

// ---------------------------------------------------------------------------
// MFMA causal flash attention, ROUND-15: attn is LDS-PORT bound (per-CU tally:
// ~29us of ds_read_b128 + ~10us Ps writes + 8us conflicts ~= the 52us dur;
// survived barrier-halving r10 and VALU-thinning r11). Fix: 32 q-rows/WAVE
// (2-wave blocks of 128 thr, same 64-row q-tile + pairing) so the shared K/V
// fragment reads amortize over 2x the q-rows -> per-CU b128 reads ~-48%.
// Q frags hoisted into registers once per pass (Qs never rewritten in-loop).
// 512 blocks x 2 waves = 1 wave/SIMD -> VGPR budget 512, no spill risk.
// Same exact shift-by-0 softmax, hw cvt, diagonal-only mask, 128-key tiles.
// Verified MFMA layouts: A: m=lane&15,k=quad*8+j; C/D: col=lane&15,row=quad*4+r.
// ---------------------------------------------------------------------------
__global__ __launch_bounds__(128) void attn_kernel(
    const u16* __restrict__ qkv, const u16* __restrict__ vt,
    u16* __restrict__ attnbuf)
{
  const int h   = blockIdx.y;
  const int kvh = h >> 2;                  // GQA group = 4
  const int tid = threadIdx.x;             // 0..127
  const int w = tid >> 6, lane = tid & 63;
  const int quad = lane >> 4, l16 = lane & 15;

  __shared__ __align__(16) u16 Qs[64][72];
  __shared__ __align__(16) u16 Ks[128][72];
  __shared__ __align__(16) u16 Vh[2][64][72];
  __shared__ __align__(16) u16 Ps[2][32][72];

  const int kcol = 2048 + kvh * 64;

#pragma unroll 1
  for (int pass = 0; pass < 2; ++pass) {
    const int bx = pass ? (31 - blockIdx.x) : blockIdx.x;
    const int r0 = bx * 64;
    const int nhalf  = bx + 1;           // 64-key halves to process
    const int ntiles = (bx + 2) >> 1;    // 128-key tiles to stage

    __syncthreads();                     // prev pass's LDS reads done

    // stage Q (already 2^-3-scaled upstream): 512 chunks, 4/thread
#pragma unroll
    for (int i = 0; i < 4; ++i) {
      const int idx = tid + i * 128;
      const int r = idx >> 3, dc = (idx & 7) * 8;
      *(uint4*)&Qs[r][dc] =
          *(const uint4*)(qkv + (size_t)(r0 + r) * 3072 + h * 64 + dc);
    }
    __syncthreads();                     // Q published

    // hoist Q A-frags for this wave's 32 q-rows (2 tiles of 16)
    bf16x8 aq[2][2];
#pragma unroll
    for (int t = 0; t < 2; ++t) {
      aq[t][0] = *(const bf16x8*)&Qs[w * 32 + t * 16 + l16][quad * 8];
      aq[t][1] = *(const bf16x8*)&Qs[w * 32 + t * 16 + l16][32 + quad * 8];
    }

    fx4 O[2][4];
    float l_r[2][4];
#pragma unroll
    for (int t = 0; t < 2; ++t)
#pragma unroll
      for (int c = 0; c < 4; ++c) O[t][c] = fx4{0.f, 0.f, 0.f, 0.f};
#pragma unroll
    for (int t = 0; t < 2; ++t)
#pragma unroll
      for (int r = 0; r < 4; ++r) l_r[t][r] = 0.f;

#pragma unroll 1
    for (int kt = 0; kt < ntiles; ++kt) {
      const int k0 = kt * 128;
      __syncthreads();                   // prev stage's LDS reads done
#pragma unroll
      for (int i = 0; i < 8; ++i) {      // stage K 128x64: 1024 chunks
        const int idx = tid + i * 128;
        const int j = idx >> 3, dc = (idx & 7) * 8;
        *(uint4*)&Ks[j][dc] =
            *(const uint4*)(qkv + (size_t)(k0 + j) * 3072 + kcol + dc);
      }
#pragma unroll
      for (int i = 0; i < 8; ++i) {      // stage V^T as two 64x64 halves
        const int idx = tid + i * 128;
        const int hh = idx >> 9, rem = idx & 511;
        const int j = rem >> 3, dc = (rem & 7) * 8;
        *(uint4*)&Vh[hh][j][dc] =
            *(const uint4*)(vt + (size_t)(kvh * 64 + j) * 2048 + k0 + hh * 64 + dc);
      }
      __syncthreads();                   // publish (one drain / 128 keys)

#pragma unroll
      for (int hh = 0; hh < 2; ++hh) {
        const int half = kt * 2 + hh;
        if (half < nhalf) {
          const int k0h = k0 + hh * 64;

          // QK^T: 32 q-rows x 64 keys (K-frags read ONCE, used by both tiles)
          fx4 sc[2][4];
#pragma unroll
          for (int c = 0; c < 4; ++c) {
            const bf16x8 b0 = *(const bf16x8*)&Ks[hh * 64 + c * 16 + l16][quad * 8];
            const bf16x8 b1 = *(const bf16x8*)&Ks[hh * 64 + c * 16 + l16][32 + quad * 8];
#pragma unroll
            for (int t = 0; t < 2; ++t) {
              fx4 z = fx4{0.f, 0.f, 0.f, 0.f};
              z        = __builtin_amdgcn_mfma_f32_16x16x32_bf16(aq[t][0], b0, z, 0, 0, 0);
              sc[t][c] = __builtin_amdgcn_mfma_f32_16x16x32_bf16(aq[t][1], b1, z, 0, 0, 0);
            }
          }

          if (k0h >= r0) {               // diagonal half: masked exp
#pragma unroll
            for (int t = 0; t < 2; ++t)
#pragma unroll
              for (int c = 0; c < 4; ++c)
#pragma unroll
                for (int r = 0; r < 4; ++r) {
                  float p = __expf(sc[t][c][r]);
                  if (k0h + c * 16 + l16 > r0 + w * 32 + t * 16 + quad * 4 + r) p = 0.f;
                  l_r[t][r] += p;
                  Ps[w][t * 16 + quad * 4 + r][c * 16 + l16] = f2b_hw(p);
                }
          } else {                       // interior half: plain exp
#pragma unroll
            for (int t = 0; t < 2; ++t)
#pragma unroll
              for (int c = 0; c < 4; ++c)
#pragma unroll
                for (int r = 0; r < 4; ++r) {
                  const float p = __expf(sc[t][c][r]);
                  l_r[t][r] += p;
                  Ps[w][t * 16 + quad * 4 + r][c * 16 + l16] = f2b_hw(p);
                }
          }

          // PV: O[32q x 64d] += P[32q x 64k] * V[64k x 64d]
          bf16x8 ap[2][2];
#pragma unroll
          for (int t = 0; t < 2; ++t) {
            ap[t][0] = *(const bf16x8*)&Ps[w][t * 16 + l16][quad * 8];
            ap[t][1] = *(const bf16x8*)&Ps[w][t * 16 + l16][32 + quad * 8];
          }
#pragma unroll
          for (int c = 0; c < 4; ++c) {
            const bf16x8 v0 = *(const bf16x8*)&Vh[hh][c * 16 + l16][quad * 8];
            const bf16x8 v1 = *(const bf16x8*)&Vh[hh][c * 16 + l16][32 + quad * 8];
#pragma unroll
            for (int t = 0; t < 2; ++t) {
              O[t][c] = __builtin_amdgcn_mfma_f32_16x16x32_bf16(ap[t][0], v0, O[t][c], 0, 0, 0);
              O[t][c] = __builtin_amdgcn_mfma_f32_16x16x32_bf16(ap[t][1], v1, O[t][c], 0, 0, 0);
            }
          }
        }
      }
    }

    // epilogue: reduce l across the 16 lanes of the quad, divide, store
#pragma unroll
    for (int t = 0; t < 2; ++t)
#pragma unroll
      for (int r = 0; r < 4; ++r) {
        float l = l_r[t][r];
#pragma unroll
        for (int off = 1; off < 16; off <<= 1) l += __shfl_xor(l, off, 64);
        const float inv = 1.f / fmaxf(l, 1e-30f);
        const int qg = r0 + w * 32 + t * 16 + quad * 4 + r;
#pragma unroll
        for (int c = 0; c < 4; ++c)
          attnbuf[(size_t)qg * 2048 + h * 64 + c * 16 + l16] =
              f2b_hw(O[t][c][r] * inv);
      }
  }
}

// ---------------------------------------------------------------------------
extern "C" void kernel_launch(void* const* d_in, const int* in_sizes, int n_in,
                              void* d_out, int out_size, void* d_ws, size_t ws_size,
                              hipStream_t stream) {
  const float* x    = (const float*)d_in[0];
  const float* Wq   = (const float*)d_in[1];
  const float* Wk   = (const float*)d_in[2];
  const float* Wv   = (const float*)d_in[3];
  const float* Wo   = (const float*)d_in[4];
  const float* cosb = (const float*)d_in[5];
  const float* sinb = (const float*)d_in[6];
  // d_in[7] = attn_mask (causal, applied structurally); d_in[8] = last_pos (=S)
  float* out = (float*)d_out;

  u16* ws      = (u16*)d_ws;
  u16* qkv     = ws;                          // 2048x3072 bf16 (Q 2^-3+roped, K roped)
  u16* attnbuf = ws + 6291456;                // 2048x2048 bf16
  u16* xb      = ws + 10485760;               // 2048x2048 bf16
  u16* Wqb     = ws + 14680064;               // 2048x2048
  u16* Wkb     = ws + 18874368;               //  512x2048
  u16* Wvb     = ws + 19922944;               //  512x2048
  u16* Wob     = ws + 20971520;               // 2048x2048
  u16* vtg     = ws + 25165824;               //  512x2048 (V^T per kv head)

  // 1) cast inputs to bf16
  cast_kernel<<<7168, 256, 0, stream>>>(x, Wq, Wk, Wv, Wo, xb);

  // 2) QKV projection + fused RoPE/Q-scale + fused V-transpose (r11 GEMM)
  gemm_bt<0><<<dim3(24, 16), 256, 0, stream>>>(
      xb, Wqb, Wkb, Wvb, qkv, 2048, 2048, 2560, 3072, cosb, sinb, vtg);

  // 3) causal MFMA flash attention: 16 balanced tile-pairs x 32 heads,
  //    128-thread blocks (2 waves x 32 q-rows)
  attn_kernel<<<dim3(16, 32), 128, 0, stream>>>(qkv, vtg, attnbuf);

  // 4) output projection (f32 out, r11 GEMM)
  gemm_bt<1><<<dim3(16, 16), 256, 0, stream>>>(
      attnbuf, Wob, Wob, Wob, out, 2048, 1 << 30, 1 << 30, 2048, cosb, sinb, vtg);
}